// Round 9
// baseline (43.490 us; speedup 1.0000x reference)
//
#include <hip/hip_runtime.h>
#include <stdint.h>

typedef __bf16 bf16x8 __attribute__((ext_vector_type(8)));
typedef float f32x4 __attribute__((ext_vector_type(4)));

#define EPS 1e-5f

// ---- workspace layout (bytes) ----
#define OFF_SQ    0                       // 192*4 f32: per-block qkv BN partials
#define OFF_Q     4096                    // q,k,v f32 128x2048 each = 3 MB
#define OFF_AHI   (OFF_Q + 3145728)       // attn bf16 128x2048 = 512 KB
#define OFF_SO    (OFF_AHI + 524288)      // 128*4 f32: out BN partials
#define OFF_PROJ  (OFF_SO + 4096)         // 128x1024 f32 = 512 KB

static __device__ __forceinline__ unsigned short f2b(float f) {
  return __builtin_bit_cast(unsigned short, (__bf16)f);
}

__device__ __forceinline__ float wave_red(float v) {
#pragma unroll
  for (int o = 32; o > 0; o >>= 1) v += __shfl_down(v, o);
  return v;
}

#define GLDS16(g, l)                                             \
  __builtin_amdgcn_global_load_lds(                              \
      (const __attribute__((address_space(1))) void*)(g),        \
      (__attribute__((address_space(3))) void*)(l), 16, 0, 0)

// Read global f32 chunks c0 (even) and c0+1 from a swizzled LDS row.
// Position p holds global chunk p ^ s (s = row&7): low-3-bit flip -> banks
// spread across all 8 groups, conflict-free. Pair is at q0 and q0^1.
static __device__ __forceinline__ void frag_split(const float* base, int c0, int s,
                                                  bf16x8& hi, bf16x8& lo) {
  int q0 = c0 ^ s;
  float4 v0 = *(const float4*)(base + q0 * 4);
  float4 v1 = *(const float4*)(base + (q0 ^ 1) * 4);
  float a[8] = {v0.x, v0.y, v0.z, v0.w, v1.x, v1.y, v1.z, v1.w};
#pragma unroll
  for (int i = 0; i < 8; ++i) {
    __bf16 h = (__bf16)a[i];
    hi[i] = h;
    lo[i] = (__bf16)(a[i] - (float)h);
  }
}
static __device__ __forceinline__ bf16x8 frag_cvt(const float* base, int c0, int s) {
  int q0 = c0 ^ s;
  float4 v0 = *(const float4*)(base + q0 * 4);
  float4 v1 = *(const float4*)(base + (q0 ^ 1) * 4);
  bf16x8 r;
  r[0] = (__bf16)v0.x; r[1] = (__bf16)v0.y; r[2] = (__bf16)v0.z; r[3] = (__bf16)v0.w;
  r[4] = (__bf16)v1.x; r[5] = (__bf16)v1.y; r[6] = (__bf16)v1.z; r[7] = (__bf16)v1.w;
  return r;
}

// K1: fused Q/K/V GEMM, split-precision (hh+hl+lh). 512 threads (8 waves =
// 2 waves/SIMD TLP). A = x f32 2-buf 1-ahead (L2-resident); B = W f32 3-buf
// 2-ahead (cold HBM). hi/lo conversion at fragment read. Counted vmcnt.
// BM=128, BN=32, BK=64, K=1024 (16 iters). grid = 3 mats x 64 nt = 192.
__global__ __launch_bounds__(512) void qkv_gemm(const float* __restrict__ x,
                                                const float* __restrict__ Wq,
                                                const float* __restrict__ Wk,
                                                const float* __restrict__ Wv,
                                                float* __restrict__ qkv,
                                                float* __restrict__ sq) {
  __shared__ alignas(16) float Af[2][128 * 64];   // 64 KB
  __shared__ alignas(16) float Bf[3][32 * 64];    // 24 KB
  __shared__ float red[32];

  int mat = blockIdx.x >> 6;
  int nt  = blockIdx.x & 63;
  const float* W = (mat == 0) ? Wq : ((mat == 1) ? Wk : Wv);
  float* outp = qkv + mat * 262144;

  int tid = threadIdx.x, w = tid >> 6, lane = tid & 63;   // w in 0..7
  int rsel = lane >> 4, ch = lane & 15, l15 = lane & 15;

  // A staging: 4 glds/thread (rows w*16 + j*4 + rsel, chunk ch, swizzled src)
#define STAGE_A(c, tt) do {                                                   \
    _Pragma("unroll")                                                         \
    for (int j = 0; j < 4; ++j) {                                             \
      int rl = w * 16 + j * 4 + rsel;                                         \
      GLDS16(x + rl * 1024 + (tt) * 64 + ((ch ^ (rl & 7)) << 2),              \
             &Af[c][(w * 16 + j * 4) * 64]);                                  \
    }                                                                         \
  } while (0)

  // B staging: 1 glds/thread (rows w*4 + (lane>>4), chunk lane&15)
#define STAGE_B(c, tt) do {                                                   \
    int rl = w * 4 + rsel;                                                    \
    GLDS16(W + (nt * 32 + rl) * 1024 + (tt) * 64 + ((ch ^ (rl & 7)) << 2),    \
           &Bf[c][(w * 4) * 64]);                                             \
  } while (0)

  f32x4 acc[2];
  acc[0] = (f32x4){0.f, 0.f, 0.f, 0.f};
  acc[1] = (f32x4){0.f, 0.f, 0.f, 0.f};

  // prologue: A(0)->buf0, B(0)->buf0, B(1)->buf1; keep B(1) in flight
  STAGE_A(0, 0);
  STAGE_B(0, 0);
  STAGE_B(1, 1);
  asm volatile("s_waitcnt vmcnt(1) lgkmcnt(0)" ::: "memory");
  __builtin_amdgcn_sched_barrier(0);
  __builtin_amdgcn_s_barrier();
  __builtin_amdgcn_sched_barrier(0);

  const int ra = w * 16 + l15;
#pragma unroll
  for (int t = 0; t < 16; ++t) {
    const int cA = t & 1, cB = t % 3;
    bf16x8 fah[2], fal[2], fbh[2][2], fbl[2][2];
#pragma unroll
    for (int ks = 0; ks < 2; ++ks) {
      int kc = ks * 4 + rsel;
      frag_split(&Af[cA][ra * 64], kc * 2, ra & 7, fah[ks], fal[ks]);
#pragma unroll
      for (int n = 0; n < 2; ++n) {
        int rb = n * 16 + l15;
        frag_split(&Bf[cB][rb * 64], kc * 2, rb & 7, fbh[ks][n], fbl[ks][n]);
      }
    }
    if (t < 15) { STAGE_A((t + 1) & 1, t + 1); }   // needed next iter
    if (t < 14) { STAGE_B((t + 2) % 3, t + 2); }   // 2 ahead, may stay in flight
#pragma unroll
    for (int ks = 0; ks < 2; ++ks)
#pragma unroll
      for (int n = 0; n < 2; ++n) {
        acc[n] = __builtin_amdgcn_mfma_f32_16x16x32_bf16(fah[ks], fbh[ks][n], acc[n], 0, 0, 0);
        acc[n] = __builtin_amdgcn_mfma_f32_16x16x32_bf16(fah[ks], fbl[ks][n], acc[n], 0, 0, 0);
        acc[n] = __builtin_amdgcn_mfma_f32_16x16x32_bf16(fal[ks], fbh[ks][n], acc[n], 0, 0, 0);
      }
    if (t < 15) {
      if (t < 14) { asm volatile("s_waitcnt vmcnt(1) lgkmcnt(0)" ::: "memory"); }
      else        { asm volatile("s_waitcnt vmcnt(0) lgkmcnt(0)" ::: "memory"); }
      __builtin_amdgcn_sched_barrier(0);
      __builtin_amdgcn_s_barrier();
      __builtin_amdgcn_sched_barrier(0);
    }
  }
#undef STAGE_A
#undef STAGE_B

  // epilogue: store f32 + per-channel (row parity) partial stats, deterministic
  float s0 = 0, q0 = 0, s1 = 0, q1 = 0;
#pragma unroll
  for (int n = 0; n < 2; ++n)
#pragma unroll
    for (int r = 0; r < 4; ++r) {
      int row = w * 16 + rsel * 4 + r;
      int col = nt * 32 + n * 16 + l15;
      float v = acc[n][r];
      outp[row * 2048 + col] = v;
      if (r & 1) { s1 += v; q1 += v * v; } else { s0 += v; q0 += v * v; }
    }
  s0 = wave_red(s0); q0 = wave_red(q0); s1 = wave_red(s1); q1 = wave_red(q1);
  if (lane == 0) { red[w * 4 + 0] = s0; red[w * 4 + 1] = q0; red[w * 4 + 2] = s1; red[w * 4 + 3] = q1; }
  __syncthreads();
  if (tid == 0) {
    float a0 = 0, a1 = 0, a2 = 0, a3 = 0;
    for (int i = 0; i < 8; ++i) { a0 += red[i * 4 + 0]; a1 += red[i * 4 + 1]; a2 += red[i * 4 + 2]; a3 += red[i * 4 + 3]; }
    *(float4*)(sq + blockIdx.x * 4) = (float4){a0, a1, a2, a3};
  }
}

// K2: per-(b,h) linear attention; reduces qkv stat partials in-kernel;
// writes attn as single bf16.
__global__ __launch_bounds__(256) void attn_kernel(const float* __restrict__ qkv,
                                                   const float* __restrict__ sq,
                                                   ushort* __restrict__ ahi,
                                                   const float* __restrict__ g_q, const float* __restrict__ b_q,
                                                   const float* __restrict__ g_k, const float* __restrict__ b_k,
                                                   const float* __restrict__ g_v, const float* __restrict__ b_v) {
  __shared__ float sm[12];
  __shared__ float red[16];
  __shared__ float bc[4];
  int bh = blockIdx.x, b = bh >> 1, h = bh & 1;
  int tid = threadIdx.x, w = tid >> 6, lane = tid & 63;

  // reduce 192 per-block partials: wave w (w<3) handles mat w (64 entries)
  if (tid < 192) {
    float4 p = *(const float4*)(sq + tid * 4);
    float a0 = wave_red(p.x), a1 = wave_red(p.y), a2 = wave_red(p.z), a3 = wave_red(p.w);
    if (lane == 0) { sm[w * 4 + 0] = a0; sm[w * 4 + 1] = a1; sm[w * 4 + 2] = a2; sm[w * 4 + 3] = a3; }
  }
  __syncthreads();

  const float cnt = 131072.f;
  float qs[2], qo[2], kc_[2], ko[2], vs[2], vo[2];
#pragma unroll
  for (int c = 0; c < 2; ++c) {
    float m, var, inv;
    m = sm[0 + 2 * c] / cnt; var = sm[1 + 2 * c] / cnt - m * m; inv = rsqrtf(var + EPS);
    qs[c] = g_q[c] * inv; qo[c] = b_q[c] - m * qs[c];
    m = sm[4 + 2 * c] / cnt; var = sm[5 + 2 * c] / cnt - m * m; inv = rsqrtf(var + EPS);
    kc_[c] = g_k[c] * inv; ko[c] = b_k[c] - m * kc_[c];
    m = sm[8 + 2 * c] / cnt; var = sm[9 + 2 * c] / cnt - m * m; inv = rsqrtf(var + EPS);
    vs[c] = g_v[c] * inv; vo[c] = b_v[c] - m * vs[c];
  }

  const float* Q = qkv;
  const float* K = qkv + 262144;
  const float* V = qkv + 524288;
  const float* q0p = Q + (b * 2 + 0) * 2048 + h * 1024;
  const float* q1p = Q + (b * 2 + 1) * 2048 + h * 1024;
  const float* k0p = K + (b * 2 + 0) * 2048 + h * 1024;
  const float* k1p = K + (b * 2 + 1) * 2048 + h * 1024;
  const float* v0p = V + (b * 2 + 0) * 2048 + h * 1024;
  const float* v1p = V + (b * 2 + 1) * 2048 + h * 1024;

  float p00 = 0, p01 = 0, p10 = 0, p11 = 0;
#pragma unroll
  for (int i = 0; i < 4; ++i) {
    int d = tid + i * 256;
    float a0 = q0p[d] * qs[0] + qo[0];
    float a1 = q1p[d] * qs[1] + qo[1];
    float c0 = k0p[d] * kc_[0] + ko[0];
    float c1 = k1p[d] * kc_[1] + ko[1];
    p00 += a0 * c0; p01 += a0 * c1; p10 += a1 * c0; p11 += a1 * c1;
  }
  p00 = wave_red(p00); p01 = wave_red(p01); p10 = wave_red(p10); p11 = wave_red(p11);
  if (lane == 0) { red[w * 4 + 0] = p00; red[w * 4 + 1] = p01; red[w * 4 + 2] = p10; red[w * 4 + 3] = p11; }
  __syncthreads();
  if (tid < 4) bc[tid] = red[0 + tid] + red[4 + tid] + red[8 + tid] + red[12 + tid];
  __syncthreads();
  float s00 = bc[0], s01 = bc[1], s10 = bc[2], s11 = bc[3];
  float di0 = 1.f / (s00 + s01), di1 = 1.f / (s10 + s11);
  int o0 = (b * 2 + 0) * 2048 + h * 1024;
  int o1 = (b * 2 + 1) * 2048 + h * 1024;
#pragma unroll
  for (int i = 0; i < 4; ++i) {
    int d = tid + i * 256;
    float v0 = v0p[d] * vs[0] + vo[0];
    float v1 = v1p[d] * vs[1] + vo[1];
    ahi[o0 + d] = f2b((s00 * v0 + s01 * v1) * di0);
    ahi[o1 + d] = f2b((s10 * v0 + s11 * v1) * di1);
  }
}

// K3: out GEMM full-K (128x2048 @ Wo^T -> 128x1024), plain bf16.
// A = attn bf16 via glds; B = Wo f32 via glds, cvt on read.
// BM=64, BN=16, BK=128, K=2048 (16 iters). grid = 2 mt x 64 nt = 128.
__global__ __launch_bounds__(256) void out_gemm(const ushort* __restrict__ ahi,
                                                const float* __restrict__ Wo,
                                                const float* __restrict__ bo,
                                                float* __restrict__ proj,
                                                float* __restrict__ so) {
  __shared__ alignas(16) ushort Ab[3][64 * 128];   // 48 KB
  __shared__ alignas(16) float  Bf[3][16 * 128];   // 24 KB
  __shared__ float red[16];

  int mt = blockIdx.x >> 6;
  int nt = blockIdx.x & 63;

  int tid = threadIdx.x, w = tid >> 6, lane = tid & 63;
  int rsel4 = lane >> 4, ch16 = lane & 15;
  int rsel2 = lane >> 5, ch32 = lane & 31;

#define STAGE_O(c, tt) do {                                                   \
    _Pragma("unroll")                                                         \
    for (int j = 0; j < 4; ++j) {                                             \
      int rl = w * 16 + j * 4 + rsel4;                                        \
      GLDS16(ahi + (mt * 64 + rl) * 2048 + (tt) * 128 +                       \
                 ((ch16 ^ (rl & 7)) << 3),                                    \
             &Ab[c][(w * 16 + j * 4) * 128]);                                 \
    }                                                                         \
    _Pragma("unroll")                                                         \
    for (int j = 0; j < 2; ++j) {                                             \
      int rl = w * 4 + j * 2 + rsel2;                                         \
      GLDS16(Wo + (nt * 16 + rl) * 2048 + (tt) * 128 +                        \
                 ((ch32 ^ (rl & 7)) << 2),                                    \
             &Bf[c][(w * 4 + j * 2) * 128]);                                  \
    }                                                                         \
  } while (0)

  f32x4 acc = (f32x4){0.f, 0.f, 0.f, 0.f};

  STAGE_O(0, 0);
  STAGE_O(1, 1);
  __syncthreads();

#pragma unroll
  for (int t = 0; t < 16; ++t) {
    const int c = t % 3;
    bf16x8 fa[4], fb[4];
#pragma unroll
    for (int ks = 0; ks < 4; ++ks) {
      int kc = ks * 4 + rsel4;
      int ra = w * 16 + (lane & 15);
      fa[ks] = *(const bf16x8*)(&Ab[c][ra * 128 + ((kc ^ (ra & 7)) << 3)]);
      int rb = lane & 15;
      fb[ks] = frag_cvt(&Bf[c][rb * 128], kc * 2, rb & 7);
    }
    if (t < 14) { STAGE_O((t + 2) % 3, t + 2); }
#pragma unroll
    for (int ks = 0; ks < 4; ++ks)
      acc = __builtin_amdgcn_mfma_f32_16x16x32_bf16(fa[ks], fb[ks], acc, 0, 0, 0);
    if (t < 15) {
      if (t < 14) { asm volatile("s_waitcnt vmcnt(6) lgkmcnt(0)" ::: "memory"); }
      else        { asm volatile("s_waitcnt vmcnt(0) lgkmcnt(0)" ::: "memory"); }
      __builtin_amdgcn_sched_barrier(0);
      __builtin_amdgcn_s_barrier();
      __builtin_amdgcn_sched_barrier(0);
    }
  }
#undef STAGE_O

  // epilogue: proj = acc + bias; per-channel partial stats (deterministic)
  int col = nt * 16 + (lane & 15);
  float bov = bo[col];
  float s0 = 0, q0 = 0, s1 = 0, q1 = 0;
#pragma unroll
  for (int r = 0; r < 4; ++r) {
    int grow = mt * 64 + w * 16 + (lane >> 4) * 4 + r;
    float v = acc[r] + bov;
    proj[grow * 1024 + col] = v;
    if (r & 1) { s1 += v; q1 += v * v; } else { s0 += v; q0 += v * v; }
  }
  s0 = wave_red(s0); q0 = wave_red(q0); s1 = wave_red(s1); q1 = wave_red(q1);
  if (lane == 0) { red[w * 4 + 0] = s0; red[w * 4 + 1] = q0; red[w * 4 + 2] = s1; red[w * 4 + 3] = q1; }
  __syncthreads();
  if (tid == 0) {
    float a0 = 0, a1 = 0, a2 = 0, a3 = 0;
    for (int i = 0; i < 4; ++i) { a0 += red[i * 4 + 0]; a1 += red[i * 4 + 1]; a2 += red[i * 4 + 2]; a3 += red[i * 4 + 3]; }
    *(float4*)(so + blockIdx.x * 4) = (float4){a0, a1, a2, a3};
  }
}

// K4: reduce 128 stat partials + final BN normalize.
__global__ __launch_bounds__(256) void final_kernel(const float* __restrict__ proj,
                                                    const float* __restrict__ so,
                                                    const float* __restrict__ g_bn,
                                                    const float* __restrict__ b_bn,
                                                    float* __restrict__ out) {
  __shared__ float sm[8];
  int tid = threadIdx.x, w = tid >> 6;
  int r = blockIdx.x;
  if (tid < 128) {
    float4 p = *(const float4*)(so + tid * 4);
    float a0 = wave_red(p.x), a1 = wave_red(p.y), a2 = wave_red(p.z), a3 = wave_red(p.w);
    if ((tid & 63) == 0) { sm[w * 4 + 0] = a0; sm[w * 4 + 1] = a1; sm[w * 4 + 2] = a2; sm[w * 4 + 3] = a3; }
  }
  __syncthreads();
  float s0 = sm[0] + sm[4], q0 = sm[1] + sm[5];
  float s1 = sm[2] + sm[6], q1 = sm[3] + sm[7];
  int ch = r & 1;
  float m = (ch ? s1 : s0) / 65536.f;
  float var = (ch ? q1 : q0) / 65536.f - m * m;
  float sc = g_bn[ch] * rsqrtf(var + EPS);
  float sh = b_bn[ch] - m * sc;
  float4 v = *(const float4*)(proj + r * 1024 + tid * 4);
  float4 o = {v.x * sc + sh, v.y * sc + sh, v.z * sc + sh, v.w * sc + sh};
  *(float4*)(out + r * 1024 + tid * 4) = o;
}

extern "C" void kernel_launch(void* const* d_in, const int* in_sizes, int n_in,
                              void* d_out, int out_size, void* d_ws, size_t ws_size,
                              hipStream_t stream) {
  (void)in_sizes; (void)n_in; (void)out_size; (void)ws_size;
  const float* x    = (const float*)d_in[0];
  const float* Wq   = (const float*)d_in[1];
  const float* Wk   = (const float*)d_in[2];
  const float* Wv   = (const float*)d_in[3];
  const float* Wo   = (const float*)d_in[4];
  const float* bo   = (const float*)d_in[5];
  const float* g_q  = (const float*)d_in[6];
  const float* b_q  = (const float*)d_in[7];
  const float* g_k  = (const float*)d_in[8];
  const float* b_k  = (const float*)d_in[9];
  const float* g_v  = (const float*)d_in[10];
  const float* b_v  = (const float*)d_in[11];
  const float* g_bn = (const float*)d_in[12];
  const float* b_bn = (const float*)d_in[13];
  char* ws = (char*)d_ws;
  float* out = (float*)d_out;

  float*  sq   = (float*)(ws + OFF_SQ);
  float*  qkv  = (float*)(ws + OFF_Q);
  ushort* ahi  = (ushort*)(ws + OFF_AHI);
  float*  so   = (float*)(ws + OFF_SO);
  float*  proj = (float*)(ws + OFF_PROJ);

  hipLaunchKernelGGL(qkv_gemm,     dim3(192), dim3(512), 0, stream, x, Wq, Wk, Wv, qkv, sq);
  hipLaunchKernelGGL(attn_kernel,  dim3(128), dim3(256), 0, stream, qkv, sq, ahi,
                     g_q, b_q, g_k, b_k, g_v, b_v);
  hipLaunchKernelGGL(out_gemm,     dim3(128), dim3(256), 0, stream, ahi, Wo, bo, proj, so);
  hipLaunchKernelGGL(final_kernel, dim3(128), dim3(256), 0, stream, proj, so, g_bn, b_bn, out);
}

// Round 10
// 41.278 us; speedup vs baseline: 1.0536x; 1.0536x over previous
//
#include <hip/hip_runtime.h>
#include <stdint.h>

typedef __bf16 bf16x8 __attribute__((ext_vector_type(8)));
typedef float f32x4 __attribute__((ext_vector_type(4)));

#define EPS 1e-5f

// ---- workspace layout (bytes) ----
#define OFF_SQ    0                       // 192*4 f32: per-block qkv BN partials
#define OFF_Q     4096                    // q,k,v f32 128x2048 each = 3 MB
#define OFF_AHI   (OFF_Q + 3145728)       // attn bf16 128x2048 = 512 KB
#define OFF_SO    (OFF_AHI + 524288)      // 128*4 f32: out BN partials
#define OFF_PROJ  (OFF_SO + 4096)         // 128x1024 f32 = 512 KB

static __device__ __forceinline__ unsigned short f2b(float f) {
  return __builtin_bit_cast(unsigned short, (__bf16)f);
}

__device__ __forceinline__ float wave_red(float v) {
#pragma unroll
  for (int o = 32; o > 0; o >>= 1) v += __shfl_down(v, o);
  return v;
}

#define GLDS16(g, l)                                             \
  __builtin_amdgcn_global_load_lds(                              \
      (const __attribute__((address_space(1))) void*)(g),        \
      (__attribute__((address_space(3))) void*)(l), 16, 0, 0)

// Read global f32 chunks c0 (even) and c0+1 from a swizzled LDS row.
// Position p holds global chunk p ^ s (s = row&7): low-3-bit flip -> banks
// spread across all 8 groups, conflict-free. Pair is at q0 and q0^1.
static __device__ __forceinline__ void frag_split(const float* base, int c0, int s,
                                                  bf16x8& hi, bf16x8& lo) {
  int q0 = c0 ^ s;
  float4 v0 = *(const float4*)(base + q0 * 4);
  float4 v1 = *(const float4*)(base + (q0 ^ 1) * 4);
  float a[8] = {v0.x, v0.y, v0.z, v0.w, v1.x, v1.y, v1.z, v1.w};
#pragma unroll
  for (int i = 0; i < 8; ++i) {
    __bf16 h = (__bf16)a[i];
    hi[i] = h;
    lo[i] = (__bf16)(a[i] - (float)h);
  }
}
static __device__ __forceinline__ bf16x8 frag_cvt(const float* base, int c0, int s) {
  int q0 = c0 ^ s;
  float4 v0 = *(const float4*)(base + q0 * 4);
  float4 v1 = *(const float4*)(base + (q0 ^ 1) * 4);
  bf16x8 r;
  r[0] = (__bf16)v0.x; r[1] = (__bf16)v0.y; r[2] = (__bf16)v0.z; r[3] = (__bf16)v0.w;
  r[4] = (__bf16)v1.x; r[5] = (__bf16)v1.y; r[6] = (__bf16)v1.z; r[7] = (__bf16)v1.w;
  return r;
}

// K1: fused Q/K/V GEMM, split-precision (hh+hl+lh). A = x f32 staged via glds,
// B = W f32 staged via glds; hi/lo conversion at fragment read. 3-buffer
// rotation, stage 2 tiles ahead into the buffer freed at the last barrier.
// BM=128, BN=32, BK=64, K=1024 (16 iters). grid = 3 mats x 64 nt = 192.
__global__ __launch_bounds__(256) void qkv_gemm(const float* __restrict__ x,
                                                const float* __restrict__ Wq,
                                                const float* __restrict__ Wk,
                                                const float* __restrict__ Wv,
                                                float* __restrict__ qkv,
                                                float* __restrict__ sq) {
  __shared__ alignas(16) float Af[3][128 * 64];   // 96 KB
  __shared__ alignas(16) float Bf[3][32 * 64];    // 24 KB
  __shared__ float red[16];

  int mat = blockIdx.x >> 6;
  int nt  = blockIdx.x & 63;
  const float* W = (mat == 0) ? Wq : ((mat == 1) ? Wk : Wv);
  float* outp = qkv + mat * 262144;

  int tid = threadIdx.x, w = tid >> 6, lane = tid & 63;
  int rsel = lane >> 4, ch = lane & 15, l15 = lane & 15;

#define STAGE_Q(c, tt) do {                                                   \
    _Pragma("unroll")                                                         \
    for (int j = 0; j < 8; ++j) {                                             \
      int rl = w * 32 + j * 4 + rsel;                                         \
      GLDS16(x + rl * 1024 + (tt) * 64 + ((ch ^ (rl & 7)) << 2),              \
             &Af[c][(w * 32 + j * 4) * 64]);                                  \
    }                                                                         \
    _Pragma("unroll")                                                         \
    for (int j = 0; j < 2; ++j) {                                             \
      int rl = w * 8 + j * 4 + rsel;                                          \
      GLDS16(W + (nt * 32 + rl) * 1024 + (tt) * 64 +                          \
                 ((ch ^ (rl & 7)) << 2),                                      \
             &Bf[c][(w * 8 + j * 4) * 64]);                                   \
    }                                                                         \
  } while (0)

  f32x4 acc[2][2];
#pragma unroll
  for (int m = 0; m < 2; ++m)
#pragma unroll
    for (int n = 0; n < 2; ++n) acc[m][n] = (f32x4){0.f, 0.f, 0.f, 0.f};

  // prologue: tiles 0,1 -> bufs 0,1
  STAGE_Q(0, 0);
  STAGE_Q(1, 1);
  __syncthreads();

#pragma unroll
  for (int t = 0; t < 16; ++t) {
    const int c = t % 3;
    bf16x8 fah[2][2], fal[2][2], fbh[2][2], fbl[2][2];
#pragma unroll
    for (int ks = 0; ks < 2; ++ks) {
      int kc = ks * 4 + rsel;
#pragma unroll
      for (int m = 0; m < 2; ++m) {
        int ra = w * 32 + m * 16 + l15;
        frag_split(&Af[c][ra * 64], kc * 2, ra & 7, fah[ks][m], fal[ks][m]);
      }
#pragma unroll
      for (int n = 0; n < 2; ++n) {
        int rb = n * 16 + l15;
        frag_split(&Bf[c][rb * 64], kc * 2, rb & 7, fbh[ks][n], fbl[ks][n]);
      }
    }
    if (t < 14) { STAGE_Q((t + 2) % 3, t + 2); }   // into freed buffer
#pragma unroll
    for (int ks = 0; ks < 2; ++ks)
#pragma unroll
      for (int m = 0; m < 2; ++m)
#pragma unroll
        for (int n = 0; n < 2; ++n) {
          acc[m][n] = __builtin_amdgcn_mfma_f32_16x16x32_bf16(fah[ks][m], fbh[ks][n], acc[m][n], 0, 0, 0);
          acc[m][n] = __builtin_amdgcn_mfma_f32_16x16x32_bf16(fah[ks][m], fbl[ks][n], acc[m][n], 0, 0, 0);
          acc[m][n] = __builtin_amdgcn_mfma_f32_16x16x32_bf16(fal[ks][m], fbh[ks][n], acc[m][n], 0, 0, 0);
        }
    if (t < 15) {
      if (t < 14) { asm volatile("s_waitcnt vmcnt(10) lgkmcnt(0)" ::: "memory"); }
      else        { asm volatile("s_waitcnt vmcnt(0) lgkmcnt(0)" ::: "memory"); }
      __builtin_amdgcn_sched_barrier(0);
      __builtin_amdgcn_s_barrier();
      __builtin_amdgcn_sched_barrier(0);
    }
  }
#undef STAGE_Q

  // epilogue: store f32 + per-channel (row parity) partial stats, deterministic
  float s0 = 0, q0 = 0, s1 = 0, q1 = 0;
#pragma unroll
  for (int m = 0; m < 2; ++m)
#pragma unroll
    for (int n = 0; n < 2; ++n)
#pragma unroll
      for (int r = 0; r < 4; ++r) {
        int row = w * 32 + m * 16 + (lane >> 4) * 4 + r;
        int col = nt * 32 + n * 16 + l15;
        float v = acc[m][n][r];
        outp[row * 2048 + col] = v;
        if (r & 1) { s1 += v; q1 += v * v; } else { s0 += v; q0 += v * v; }
      }
  s0 = wave_red(s0); q0 = wave_red(q0); s1 = wave_red(s1); q1 = wave_red(q1);
  if (lane == 0) { red[w * 4 + 0] = s0; red[w * 4 + 1] = q0; red[w * 4 + 2] = s1; red[w * 4 + 3] = q1; }
  __syncthreads();
  if (tid == 0) {
    float a0 = 0, a1 = 0, a2 = 0, a3 = 0;
    for (int i = 0; i < 4; ++i) { a0 += red[i * 4 + 0]; a1 += red[i * 4 + 1]; a2 += red[i * 4 + 2]; a3 += red[i * 4 + 3]; }
    *(float4*)(sq + blockIdx.x * 4) = (float4){a0, a1, a2, a3};
  }
}

// K2: per-(b,h) linear attention; reduces qkv stat partials in-kernel;
// writes attn as single bf16.
__global__ __launch_bounds__(256) void attn_kernel(const float* __restrict__ qkv,
                                                   const float* __restrict__ sq,
                                                   ushort* __restrict__ ahi,
                                                   const float* __restrict__ g_q, const float* __restrict__ b_q,
                                                   const float* __restrict__ g_k, const float* __restrict__ b_k,
                                                   const float* __restrict__ g_v, const float* __restrict__ b_v) {
  __shared__ float sm[12];
  __shared__ float red[16];
  __shared__ float bc[4];
  int bh = blockIdx.x, b = bh >> 1, h = bh & 1;
  int tid = threadIdx.x, w = tid >> 6, lane = tid & 63;

  // reduce 192 per-block partials: wave w (w<3) handles mat w (64 entries)
  if (tid < 192) {
    float4 p = *(const float4*)(sq + tid * 4);
    float a0 = wave_red(p.x), a1 = wave_red(p.y), a2 = wave_red(p.z), a3 = wave_red(p.w);
    if (lane == 0) { sm[w * 4 + 0] = a0; sm[w * 4 + 1] = a1; sm[w * 4 + 2] = a2; sm[w * 4 + 3] = a3; }
  }
  __syncthreads();

  const float cnt = 131072.f;
  float qs[2], qo[2], kc_[2], ko[2], vs[2], vo[2];
#pragma unroll
  for (int c = 0; c < 2; ++c) {
    float m, var, inv;
    m = sm[0 + 2 * c] / cnt; var = sm[1 + 2 * c] / cnt - m * m; inv = rsqrtf(var + EPS);
    qs[c] = g_q[c] * inv; qo[c] = b_q[c] - m * qs[c];
    m = sm[4 + 2 * c] / cnt; var = sm[5 + 2 * c] / cnt - m * m; inv = rsqrtf(var + EPS);
    kc_[c] = g_k[c] * inv; ko[c] = b_k[c] - m * kc_[c];
    m = sm[8 + 2 * c] / cnt; var = sm[9 + 2 * c] / cnt - m * m; inv = rsqrtf(var + EPS);
    vs[c] = g_v[c] * inv; vo[c] = b_v[c] - m * vs[c];
  }

  const float* Q = qkv;
  const float* K = qkv + 262144;
  const float* V = qkv + 524288;
  const float* q0p = Q + (b * 2 + 0) * 2048 + h * 1024;
  const float* q1p = Q + (b * 2 + 1) * 2048 + h * 1024;
  const float* k0p = K + (b * 2 + 0) * 2048 + h * 1024;
  const float* k1p = K + (b * 2 + 1) * 2048 + h * 1024;
  const float* v0p = V + (b * 2 + 0) * 2048 + h * 1024;
  const float* v1p = V + (b * 2 + 1) * 2048 + h * 1024;

  float p00 = 0, p01 = 0, p10 = 0, p11 = 0;
#pragma unroll
  for (int i = 0; i < 4; ++i) {
    int d = tid + i * 256;
    float a0 = q0p[d] * qs[0] + qo[0];
    float a1 = q1p[d] * qs[1] + qo[1];
    float c0 = k0p[d] * kc_[0] + ko[0];
    float c1 = k1p[d] * kc_[1] + ko[1];
    p00 += a0 * c0; p01 += a0 * c1; p10 += a1 * c0; p11 += a1 * c1;
  }
  p00 = wave_red(p00); p01 = wave_red(p01); p10 = wave_red(p10); p11 = wave_red(p11);
  if (lane == 0) { red[w * 4 + 0] = p00; red[w * 4 + 1] = p01; red[w * 4 + 2] = p10; red[w * 4 + 3] = p11; }
  __syncthreads();
  if (tid < 4) bc[tid] = red[0 + tid] + red[4 + tid] + red[8 + tid] + red[12 + tid];
  __syncthreads();
  float s00 = bc[0], s01 = bc[1], s10 = bc[2], s11 = bc[3];
  float di0 = 1.f / (s00 + s01), di1 = 1.f / (s10 + s11);
  int o0 = (b * 2 + 0) * 2048 + h * 1024;
  int o1 = (b * 2 + 1) * 2048 + h * 1024;
#pragma unroll
  for (int i = 0; i < 4; ++i) {
    int d = tid + i * 256;
    float v0 = v0p[d] * vs[0] + vo[0];
    float v1 = v1p[d] * vs[1] + vo[1];
    ahi[o0 + d] = f2b((s00 * v0 + s01 * v1) * di0);
    ahi[o1 + d] = f2b((s10 * v0 + s11 * v1) * di1);
  }
}

// K3: out GEMM full-K (128x2048 @ Wo^T -> 128x1024), plain bf16.
// A = attn bf16 via glds; B = Wo f32 via glds, cvt on read.
// BM=64, BN=16, BK=128, K=2048 (16 iters). grid = 2 mt x 64 nt = 128.
__global__ __launch_bounds__(256) void out_gemm(const ushort* __restrict__ ahi,
                                                const float* __restrict__ Wo,
                                                const float* __restrict__ bo,
                                                float* __restrict__ proj,
                                                float* __restrict__ so) {
  __shared__ alignas(16) ushort Ab[3][64 * 128];   // 48 KB
  __shared__ alignas(16) float  Bf[3][16 * 128];   // 24 KB
  __shared__ float red[16];

  int mt = blockIdx.x >> 6;
  int nt = blockIdx.x & 63;

  int tid = threadIdx.x, w = tid >> 6, lane = tid & 63;
  int rsel4 = lane >> 4, ch16 = lane & 15;
  int rsel2 = lane >> 5, ch32 = lane & 31;

#define STAGE_O(c, tt) do {                                                   \
    _Pragma("unroll")                                                         \
    for (int j = 0; j < 4; ++j) {                                             \
      int rl = w * 16 + j * 4 + rsel4;                                        \
      GLDS16(ahi + (mt * 64 + rl) * 2048 + (tt) * 128 +                       \
                 ((ch16 ^ (rl & 7)) << 3),                                    \
             &Ab[c][(w * 16 + j * 4) * 128]);                                 \
    }                                                                         \
    _Pragma("unroll")                                                         \
    for (int j = 0; j < 2; ++j) {                                             \
      int rl = w * 4 + j * 2 + rsel2;                                         \
      GLDS16(Wo + (nt * 16 + rl) * 2048 + (tt) * 128 +                        \
                 ((ch32 ^ (rl & 7)) << 2),                                    \
             &Bf[c][(w * 4 + j * 2) * 128]);                                  \
    }                                                                         \
  } while (0)

  f32x4 acc = (f32x4){0.f, 0.f, 0.f, 0.f};

  STAGE_O(0, 0);
  STAGE_O(1, 1);
  __syncthreads();

#pragma unroll
  for (int t = 0; t < 16; ++t) {
    const int c = t % 3;
    bf16x8 fa[4], fb[4];
#pragma unroll
    for (int ks = 0; ks < 4; ++ks) {
      int kc = ks * 4 + rsel4;
      int ra = w * 16 + (lane & 15);
      fa[ks] = *(const bf16x8*)(&Ab[c][ra * 128 + ((kc ^ (ra & 7)) << 3)]);
      int rb = lane & 15;
      fb[ks] = frag_cvt(&Bf[c][rb * 128], kc * 2, rb & 7);
    }
    if (t < 14) { STAGE_O((t + 2) % 3, t + 2); }
#pragma unroll
    for (int ks = 0; ks < 4; ++ks)
      acc = __builtin_amdgcn_mfma_f32_16x16x32_bf16(fa[ks], fb[ks], acc, 0, 0, 0);
    if (t < 15) {
      if (t < 14) { asm volatile("s_waitcnt vmcnt(6) lgkmcnt(0)" ::: "memory"); }
      else        { asm volatile("s_waitcnt vmcnt(0) lgkmcnt(0)" ::: "memory"); }
      __builtin_amdgcn_sched_barrier(0);
      __builtin_amdgcn_s_barrier();
      __builtin_amdgcn_sched_barrier(0);
    }
  }
#undef STAGE_O

  // epilogue: proj = acc + bias; per-channel partial stats (deterministic)
  int col = nt * 16 + (lane & 15);
  float bov = bo[col];
  float s0 = 0, q0 = 0, s1 = 0, q1 = 0;
#pragma unroll
  for (int r = 0; r < 4; ++r) {
    int grow = mt * 64 + w * 16 + (lane >> 4) * 4 + r;
    float v = acc[r] + bov;
    proj[grow * 1024 + col] = v;
    if (r & 1) { s1 += v; q1 += v * v; } else { s0 += v; q0 += v * v; }
  }
  s0 = wave_red(s0); q0 = wave_red(q0); s1 = wave_red(s1); q1 = wave_red(q1);
  if (lane == 0) { red[w * 4 + 0] = s0; red[w * 4 + 1] = q0; red[w * 4 + 2] = s1; red[w * 4 + 3] = q1; }
  __syncthreads();
  if (tid == 0) {
    float a0 = 0, a1 = 0, a2 = 0, a3 = 0;
    for (int i = 0; i < 4; ++i) { a0 += red[i * 4 + 0]; a1 += red[i * 4 + 1]; a2 += red[i * 4 + 2]; a3 += red[i * 4 + 3]; }
    *(float4*)(so + blockIdx.x * 4) = (float4){a0, a1, a2, a3};
  }
}

// K4: reduce 128 stat partials + final BN normalize.
__global__ __launch_bounds__(256) void final_kernel(const float* __restrict__ proj,
                                                    const float* __restrict__ so,
                                                    const float* __restrict__ g_bn,
                                                    const float* __restrict__ b_bn,
                                                    float* __restrict__ out) {
  __shared__ float sm[8];
  int tid = threadIdx.x, w = tid >> 6;
  int r = blockIdx.x;
  if (tid < 128) {
    float4 p = *(const float4*)(so + tid * 4);
    float a0 = wave_red(p.x), a1 = wave_red(p.y), a2 = wave_red(p.z), a3 = wave_red(p.w);
    if ((tid & 63) == 0) { sm[w * 4 + 0] = a0; sm[w * 4 + 1] = a1; sm[w * 4 + 2] = a2; sm[w * 4 + 3] = a3; }
  }
  __syncthreads();
  float s0 = sm[0] + sm[4], q0 = sm[1] + sm[5];
  float s1 = sm[2] + sm[6], q1 = sm[3] + sm[7];
  int ch = r & 1;
  float m = (ch ? s1 : s0) / 65536.f;
  float var = (ch ? q1 : q0) / 65536.f - m * m;
  float sc = g_bn[ch] * rsqrtf(var + EPS);
  float sh = b_bn[ch] - m * sc;
  float4 v = *(const float4*)(proj + r * 1024 + tid * 4);
  float4 o = {v.x * sc + sh, v.y * sc + sh, v.z * sc + sh, v.w * sc + sh};
  *(float4*)(out + r * 1024 + tid * 4) = o;
}

extern "C" void kernel_launch(void* const* d_in, const int* in_sizes, int n_in,
                              void* d_out, int out_size, void* d_ws, size_t ws_size,
                              hipStream_t stream) {
  (void)in_sizes; (void)n_in; (void)out_size; (void)ws_size;
  const float* x    = (const float*)d_in[0];
  const float* Wq   = (const float*)d_in[1];
  const float* Wk   = (const float*)d_in[2];
  const float* Wv   = (const float*)d_in[3];
  const float* Wo   = (const float*)d_in[4];
  const float* bo   = (const float*)d_in[5];
  const float* g_q  = (const float*)d_in[6];
  const float* b_q  = (const float*)d_in[7];
  const float* g_k  = (const float*)d_in[8];
  const float* b_k  = (const float*)d_in[9];
  const float* g_v  = (const float*)d_in[10];
  const float* b_v  = (const float*)d_in[11];
  const float* g_bn = (const float*)d_in[12];
  const float* b_bn = (const float*)d_in[13];
  char* ws = (char*)d_ws;
  float* out = (float*)d_out;

  float*  sq   = (float*)(ws + OFF_SQ);
  float*  qkv  = (float*)(ws + OFF_Q);
  ushort* ahi  = (ushort*)(ws + OFF_AHI);
  float*  so   = (float*)(ws + OFF_SO);
  float*  proj = (float*)(ws + OFF_PROJ);

  hipLaunchKernelGGL(qkv_gemm,     dim3(192), dim3(256), 0, stream, x, Wq, Wk, Wv, qkv, sq);
  hipLaunchKernelGGL(attn_kernel,  dim3(128), dim3(256), 0, stream, qkv, sq, ahi,
                     g_q, b_q, g_k, b_k, g_v, b_v);
  hipLaunchKernelGGL(out_gemm,     dim3(128), dim3(256), 0, stream, ahi, Wo, bo, proj, so);
  hipLaunchKernelGGL(final_kernel, dim3(128), dim3(256), 0, stream, proj, so, g_bn, b_bn, out);
}